// Round 10
// baseline (1173.139 us; speedup 1.0000x reference)
//
#include <hip/hip_runtime.h>
#include <hip/hip_bf16.h>

// Problem constants (fixed by the reference problem)
#define D 128
#define GRAPHS 512
#define OUTD 64
#define NS 64         // key-range scan blocks (one exclusive node range each)
#define LRANGE 800    // LDS counters per block (>= ceil(50000/64) = 782)

typedef _Float16 half4v __attribute__((ext_vector_type(4)));
typedef _Float16 half8v __attribute__((ext_vector_type(8)));
typedef float float4v __attribute__((ext_vector_type(4)));
typedef float float8v __attribute__((ext_vector_type(8)));
typedef unsigned short u16;

// ---------------------------------------------------------------------------
// Prep (fused): blocks 0..NS-1 = key-range histogram blocks — each owns an
// exclusive node range and streams the L2-resident edge list, counting owned
// keys in LDS (NO global atomics, exact counts, no rank arrays). Remaining
// blocks stream h0 = fp16(emb[nodes]) and the W fragment pack; they overlap
// the scan. W pack layout (per layer): [src(3)][ks(4)][nf(8)][lane(64)][j(8)].
// ---------------------------------------------------------------------------
__global__ __launch_bounds__(256) void prep_kernel(
    const int* __restrict__ edges, const int* __restrict__ indices,
    int* __restrict__ cnt_in, int* __restrict__ cnt_out, int* __restrict__ gcnt,
    const int* __restrict__ nodes, const float* __restrict__ emb,
    _Float16* __restrict__ h,
    const float* __restrict__ W0, const float* __restrict__ W1,
    const float* __restrict__ W2, _Float16* __restrict__ Wpk,
    int E, int n) {
    int tid = threadIdx.x;
    if (blockIdx.x < NS) {
        __shared__ int lcnt[LRANGE];
        int b = blockIdx.x;
        int range = (n + NS - 1) / NS;
        int lo = b * range, hi = min(lo + range, n), len = hi - lo;
        const int* srcp = edges;
        const int* dstp = edges + E;
        int E4 = E >> 2;

#define HIT(k) { unsigned r_ = (unsigned)((k) - lo); if (r_ < (unsigned)len) atomicAdd(&lcnt[r_], 1); }
        // pass A: cnt_in from dst
        for (int j = tid; j < len; j += 256) lcnt[j] = 0;
        __syncthreads();
        {
            const int4* p4 = (const int4*)dstp;
            for (int it = tid; it < E4; it += 256) {
                int4 v = p4[it];
                HIT(v.x) HIT(v.y) HIT(v.z) HIT(v.w)
            }
            for (int e = E4 * 4 + tid; e < E; e += 256) HIT(dstp[e])
        }
        __syncthreads();
        for (int j = tid; j < len; j += 256) cnt_in[lo + j] = lcnt[j];
        __syncthreads();
        // pass B: cnt_out from src
        for (int j = tid; j < len; j += 256) lcnt[j] = 0;
        __syncthreads();
        {
            const int4* p4 = (const int4*)srcp;
            for (int it = tid; it < E4; it += 256) {
                int4 v = p4[it];
                HIT(v.x) HIT(v.y) HIT(v.z) HIT(v.w)
            }
            for (int e = E4 * 4 + tid; e < E; e += 256) HIT(srcp[e])
        }
        __syncthreads();
        for (int j = tid; j < len; j += 256) cnt_out[lo + j] = lcnt[j];
        __syncthreads();
#undef HIT
        // pass C: gcnt from indices (each block owns GRAPHS/NS graphs)
        int grange = (GRAPHS + NS - 1) / NS;
        int glo = b * grange, ghi = min(glo + grange, GRAPHS), glen = ghi - glo;
        for (int j = tid; j < glen; j += 256) lcnt[j] = 0;
        __syncthreads();
#define GHIT(k) { unsigned r_ = (unsigned)((k) - glo); if (r_ < (unsigned)glen) atomicAdd(&lcnt[r_], 1); }
        {
            const int4* p4 = (const int4*)indices;
            int n4 = n >> 2;
            for (int it = tid; it < n4; it += 256) {
                int4 v = p4[it];
                GHIT(v.x) GHIT(v.y) GHIT(v.z) GHIT(v.w)
            }
            for (int e = n4 * 4 + tid; e < n; e += 256) GHIT(indices[e])
        }
        __syncthreads();
        for (int j = tid; j < glen; j += 256) gcnt[glo + j] = lcnt[j];
#undef GHIT
        return;
    }
    // ---- stream role: gather + W pack ----
    int i = (blockIdx.x - NS) * 256 + tid;
    if (i < n * 16) {   // gather: n*16 half8 chunks (16B/lane)
        int v = i >> 4, q = i & 15;
        const float4* e4 = (const float4*)emb + (size_t)nodes[v] * 32 + q * 2;
        float4 f0 = e4[0];
        float4 f1 = e4[1];
        half8v o = {(_Float16)f0.x, (_Float16)f0.y, (_Float16)f0.z, (_Float16)f0.w,
                    (_Float16)f1.x, (_Float16)f1.y, (_Float16)f1.z, (_Float16)f1.w};
        ((half8v*)h)[i] = o;
    }
    if (i < 36864) {    // 3 layers * 3 srcs * 4 ks * 8 nf * 64 lanes * 2 (j4) quads
        int j4 = (i & 1) * 4;
        int t = i >> 1;
        int lane = t & 63; t >>= 6;
        int nf = t & 7;   t >>= 3;
        int ks = t & 3;   t >>= 2;
        int src = t % 3;
        int l = t / 3;
        const float* W = (src == 0 ? W0 : (src == 1 ? W1 : W2)) + l * D * D;
        int col = nf * 16 + (lane & 15);
        int k = ks * 32 + (lane >> 4) * 8 + j4;
        float4 f = *(const float4*)&W[col * D + k];
        half4v o = {(_Float16)f.x, (_Float16)f.y, (_Float16)f.z, (_Float16)f.w};
        _Float16* dst = Wpk + ((size_t)(((l * 3 + src) * 4 + ks) * 8 + nf) * 64 + lane) * 8 + j4;
        *(half4v*)dst = o;
    }
}

// ---------------------------------------------------------------------------
// Offsets via wave-scan + atomic region allocation. CSR regions need not be
// in node order — each node only needs a contiguous slice of the right size.
// blockIdx 0/1 also handle the 512 graph counters.
// ---------------------------------------------------------------------------
__global__ __launch_bounds__(256) void offsets_kernel(
    const int* __restrict__ c_in, int* __restrict__ o_in,
    const int* __restrict__ c_out, int* __restrict__ o_out,
    const int* __restrict__ c_g, int* __restrict__ o_g,
    int* totals, int n) {
    __shared__ int ws[8];
    int tid = threadIdx.x;
    int lane = tid & 63, wid = tid >> 6;
    int i = blockIdx.x * 256 + tid;

#define SCAN_ALLOC(cnt, off, total, len)                                   \
    do {                                                                   \
        int v_ = (i < (len)) ? (cnt)[i] : 0;                               \
        int orig_ = v_;                                                    \
        _Pragma("unroll") for (int d_ = 1; d_ < 64; d_ <<= 1) {            \
            int t_ = __shfl_up(v_, d_, 64);                                \
            if (lane >= d_) v_ += t_;                                      \
        }                                                                  \
        if (lane == 63) ws[wid] = v_;                                      \
        __syncthreads();                                                   \
        if (tid == 0) {                                                    \
            int s_ = 0;                                                    \
            for (int k_ = 0; k_ < 4; ++k_) { int t_ = ws[k_]; ws[k_] = s_; s_ += t_; } \
            ws[4] = atomicAdd((total), s_);                                \
        }                                                                  \
        __syncthreads();                                                   \
        if (i < (len)) (off)[i] = ws[4] + ws[wid] + v_ - orig_;            \
        __syncthreads();                                                   \
    } while (0)

    SCAN_ALLOC(c_in, o_in, &totals[0], n);
    SCAN_ALLOC(c_out, o_out, &totals[1], n);
    if (blockIdx.x < (GRAPHS + 255) / 256) SCAN_ALLOC(c_g, o_g, &totals[2], GRAPHS);
#undef SCAN_ALLOC
}

// ---------------------------------------------------------------------------
// Fill: NS key-range blocks, LDS cursors initialized from the global offsets.
// Each block streams the edge list and writes CSR entries for its OWN node
// range only -> every csr write lands in the block's contiguous region
// (clustered dirty lines, no global atomics, slots unique via LDS atomics).
// Third pass fills the node-by-graph list the same way.
// ---------------------------------------------------------------------------
__global__ __launch_bounds__(256) void fill_kernel(
    const int* __restrict__ edges, const int* __restrict__ indices,
    const int* __restrict__ off_in, const int* __restrict__ off_out,
    const int* __restrict__ goff,
    u16* __restrict__ csr_in, u16* __restrict__ csr_out, u16* __restrict__ glist,
    int E, int n) {
    __shared__ int cin[LRANGE];
    __shared__ int cout[LRANGE];
    __shared__ int cg[16];
    int tid = threadIdx.x;
    int b = blockIdx.x;
    int range = (n + NS - 1) / NS;
    int lo = b * range, hi = min(lo + range, n), len = hi - lo;
    int grange = (GRAPHS + NS - 1) / NS;
    int glo = b * grange, ghi = min(glo + grange, GRAPHS), glen = ghi - glo;
    for (int j = tid; j < len; j += 256) { cin[j] = off_in[lo + j]; cout[j] = off_out[lo + j]; }
    for (int j = tid; j < glen; j += 256) cg[j] = goff[glo + j];
    __syncthreads();

    const int* srcp = edges;
    const int* dstp = edges + E;
    int E4 = E >> 2;
    // pass 1: in-edges (key = dst, payload = src)
#define FIN(k, idx) { unsigned r_ = (unsigned)((k) - lo); if (r_ < (unsigned)len) { \
        int p_ = atomicAdd(&cin[r_], 1); csr_in[p_] = (u16)srcp[idx]; } }
    {
        const int4* p4 = (const int4*)dstp;
        for (int it = tid; it < E4; it += 256) {
            int4 v = p4[it]; int e = it * 4;
            FIN(v.x, e) FIN(v.y, e + 1) FIN(v.z, e + 2) FIN(v.w, e + 3)
        }
        for (int e = E4 * 4 + tid; e < E; e += 256) FIN(dstp[e], e)
    }
#undef FIN
    // pass 2: out-edges (key = src, payload = dst)
#define FOUT(k, idx) { unsigned r_ = (unsigned)((k) - lo); if (r_ < (unsigned)len) { \
        int p_ = atomicAdd(&cout[r_], 1); csr_out[p_] = (u16)dstp[idx]; } }
    {
        const int4* p4 = (const int4*)srcp;
        for (int it = tid; it < E4; it += 256) {
            int4 v = p4[it]; int e = it * 4;
            FOUT(v.x, e) FOUT(v.y, e + 1) FOUT(v.z, e + 2) FOUT(v.w, e + 3)
        }
        for (int e = E4 * 4 + tid; e < E; e += 256) FOUT(srcp[e], e)
    }
#undef FOUT
    // pass 3: node-by-graph list (key = graph, payload = node id)
#define FG(g, vv) { unsigned r_ = (unsigned)((g) - glo); if (r_ < (unsigned)glen) { \
        int p_ = atomicAdd(&cg[r_], 1); glist[p_] = (u16)(vv); } }
    {
        const int4* p4 = (const int4*)indices;
        int n4 = n >> 2;
        for (int it = tid; it < n4; it += 256) {
            int4 v = p4[it]; int e = it * 4;
            FG(v.x, e) FG(v.y, e + 1) FG(v.z, e + 2) FG(v.w, e + 3)
        }
        for (int e = n4 * 4 + tid; e < n; e += 256) FG(indices[e], e)
    }
#undef FG
}

// ---------------------------------------------------------------------------
// Aggregation (fp16 h): 16-lane group per node, lane holds 8 fp16 (16B).
// x4 unroll -> 4 independent 16B loads in flight per group. fp32 accumulate.
// ---------------------------------------------------------------------------
__global__ __launch_bounds__(256) void aggregate_kernel(
    const _Float16* __restrict__ h,
    const u16* __restrict__ csr_in, const int* __restrict__ off_in, const int* __restrict__ cnt_in,
    const u16* __restrict__ csr_out, const int* __restrict__ off_out, const int* __restrict__ cnt_out,
    _Float16* __restrict__ agg1, _Float16* __restrict__ agg2, int n) {
    int grp = threadIdx.x >> 4;   // 16 nodes / block
    int lane = threadIdx.x & 15;
    int v = blockIdx.x * 16 + grp;
    if (v >= n) return;
    int s1 = off_in[v], c1 = cnt_in[v];
    int s2 = off_out[v], c2 = cnt_out[v];
    float invd = 1.0f / fmaxf((float)(c1 + c2), 1.0f);
    const half8v* h8 = (const half8v*)h;

    float8v a1 = {0.f, 0.f, 0.f, 0.f, 0.f, 0.f, 0.f, 0.f};
    int i = 0;
    for (; i + 4 <= c1; i += 4) {
        int u0 = csr_in[s1 + i], u1 = csr_in[s1 + i + 1];
        int u2 = csr_in[s1 + i + 2], u3 = csr_in[s1 + i + 3];
        half8v p0 = h8[u0 * 16 + lane];
        half8v p1 = h8[u1 * 16 + lane];
        half8v p2 = h8[u2 * 16 + lane];
        half8v p3 = h8[u3 * 16 + lane];
        a1 += (__builtin_convertvector(p0, float8v) + __builtin_convertvector(p1, float8v)) +
              (__builtin_convertvector(p2, float8v) + __builtin_convertvector(p3, float8v));
    }
    for (; i < c1; ++i)
        a1 += __builtin_convertvector(h8[csr_in[s1 + i] * 16 + lane], float8v);

    float8v a2 = {0.f, 0.f, 0.f, 0.f, 0.f, 0.f, 0.f, 0.f};
    i = 0;
    for (; i + 4 <= c2; i += 4) {
        int u0 = csr_out[s2 + i], u1 = csr_out[s2 + i + 1];
        int u2 = csr_out[s2 + i + 2], u3 = csr_out[s2 + i + 3];
        half8v p0 = h8[u0 * 16 + lane];
        half8v p1 = h8[u1 * 16 + lane];
        half8v p2 = h8[u2 * 16 + lane];
        half8v p3 = h8[u3 * 16 + lane];
        a2 += (__builtin_convertvector(p0, float8v) + __builtin_convertvector(p1, float8v)) +
              (__builtin_convertvector(p2, float8v) + __builtin_convertvector(p3, float8v));
    }
    for (; i < c2; ++i)
        a2 += __builtin_convertvector(h8[csr_out[s2 + i] * 16 + lane], float8v);

    a1 *= invd;
    a2 *= invd;
    ((half8v*)agg1)[v * 16 + lane] = __builtin_convertvector(a1, half8v);
    ((half8v*)agg2)[v * 16 + lane] = __builtin_convertvector(a2, half8v);
}

// ---------------------------------------------------------------------------
// MFMA transform: Hout = relu(H@W0^T + A1@W1^T + A2@W2^T), all fp16 in/out,
// fp32 accumulate. BM=64 rows/block, 2 waves; wave w owns rows w*32..+31
// (2 m-frags x 8 n-frags of 16x16x32_f16). A-frags read straight from global
// (own rows only -> self-aliasing with Hout is safe); B-frags read from the
// pre-packed, L2-resident Wpk (lane*16B contiguous). No LDS in the K-loop.
// Fragment maps: A/B k = 8*(lane>>4)+j (m92-verified contiguous-k);
// C/D n = lane&15, m = 4*(lane>>4)+reg (m89/m91-verified).
// ---------------------------------------------------------------------------
__global__ __launch_bounds__(128) void transform_mfma(
    const _Float16* __restrict__ Xh, const _Float16* __restrict__ A1,
    const _Float16* __restrict__ A2, const _Float16* __restrict__ Wl,
    _Float16* __restrict__ Hout, int n) {
    __shared__ _Float16 Hs[64][136];   // epilogue transpose tile (stride 272B)
    int tid = threadIdx.x;
    int w = tid >> 6, lane = tid & 63;
    int rbase = blockIdx.x * 64 + w * 32;
    int m0 = lane & 15;
    int kg = lane >> 4;                 // 0..3
    int r0 = min(rbase + m0, n - 1);        // clamp keeps tail loads in-bounds
    int r1 = min(rbase + 16 + m0, n - 1);

    const _Float16* srcs[3] = {Xh, A1, A2};

    float4v acc[2][8];
#pragma unroll
    for (int mf = 0; mf < 2; ++mf)
#pragma unroll
        for (int nf = 0; nf < 8; ++nf) acc[mf][nf] = (float4v){0.f, 0.f, 0.f, 0.f};

#define LOAD_STEP(stp, A0v, A1v, Bv)                                              \
    do {                                                                          \
        const int src_ = (stp) >> 2, ks_ = (stp) & 3;                             \
        const _Float16* X_ = srcs[src_];                                          \
        A0v = *(const half8v*)(X_ + (size_t)r0 * D + ks_ * 32 + kg * 8);          \
        A1v = *(const half8v*)(X_ + (size_t)r1 * D + ks_ * 32 + kg * 8);          \
        const _Float16* wp_ = Wl + (size_t)((src_ * 4 + ks_) * 8) * 512 + lane * 8; \
        _Pragma("unroll") for (int nf_ = 0; nf_ < 8; ++nf_)                       \
            Bv[nf_] = *(const half8v*)(wp_ + nf_ * 512);                          \
    } while (0)

    half8v a0c, a1c, bc[8], a0n, a1n, bn[8];
    LOAD_STEP(0, a0c, a1c, bc);
#pragma unroll
    for (int step = 0; step < 12; ++step) {
        if (step < 11) LOAD_STEP(step + 1, a0n, a1n, bn);
#pragma unroll
        for (int nf = 0; nf < 8; ++nf) {
            acc[0][nf] = __builtin_amdgcn_mfma_f32_16x16x32_f16(a0c, bc[nf], acc[0][nf], 0, 0, 0);
            acc[1][nf] = __builtin_amdgcn_mfma_f32_16x16x32_f16(a1c, bc[nf], acc[1][nf], 0, 0, 0);
        }
        a0c = a0n; a1c = a1n;
#pragma unroll
        for (int nf = 0; nf < 8; ++nf) bc[nf] = bn[nf];
    }
#undef LOAD_STEP

    // epilogue: relu -> LDS transpose -> coalesced fp16 row stores
#pragma unroll
    for (int mf = 0; mf < 2; ++mf)
#pragma unroll
        for (int nf = 0; nf < 8; ++nf)
#pragma unroll
            for (int r = 0; r < 4; ++r) {
                int row = w * 32 + mf * 16 + kg * 4 + r;
                int col = nf * 16 + m0;
                Hs[row][col] = (_Float16)fmaxf(acc[mf][nf][r], 0.0f);
            }
    __syncthreads();
#pragma unroll
    for (int it = 0; it < 8; ++it) {
        int id = tid + it * 128;        // 0..1023 = 64 rows x 16 chunks of 8 fp16
        int row = id >> 4, c8 = id & 15;
        int grow = blockIdx.x * 64 + row;
        if (grow < n)
            *(half8v*)(Hout + (size_t)grow * D + c8 * 8) = *(const half8v*)&Hs[row][c8 * 8];
    }
}

// ---------------------------------------------------------------------------
// Graph pooling + output head, fused. One block (128 threads) per graph.
// mean + max over the graph's node list (h >= 0 post-ReLU so max-init 0
// matches torch_scatter's empty->0 default), then out = [mean|max]@Wout+bout.
// ---------------------------------------------------------------------------
__global__ __launch_bounds__(128) void pool_head_kernel(
    const _Float16* __restrict__ h, const u16* __restrict__ glist,
    const int* __restrict__ goff, const int* __restrict__ gcnt,
    const float* __restrict__ Wout, const float* __restrict__ bout,
    float* __restrict__ out) {
    __shared__ float feat[2 * D];
    int g = blockIdx.x;
    int t = threadIdx.x;
    int s = goff[g], c = gcnt[g];
    float sum = 0.0f, mx = 0.0f;
    int i = 0;
    for (; i + 4 <= c; i += 4) {
        int v0 = glist[s + i], v1 = glist[s + i + 1];
        int v2 = glist[s + i + 2], v3 = glist[s + i + 3];
        float a = (float)h[(size_t)v0 * D + t];
        float b = (float)h[(size_t)v1 * D + t];
        float cc = (float)h[(size_t)v2 * D + t];
        float d = (float)h[(size_t)v3 * D + t];
        sum += (a + b) + (cc + d);
        mx = fmaxf(mx, fmaxf(fmaxf(a, b), fmaxf(cc, d)));
    }
    for (; i < c; ++i) {
        float a = (float)h[(size_t)glist[s + i] * D + t];
        sum += a;
        mx = fmaxf(mx, a);
    }
    feat[t] = sum / fmaxf((float)c, 1.0f);
    feat[D + t] = mx;
    __syncthreads();
    if (t < OUTD) {
        float acc = bout[t];
#pragma unroll 8
        for (int k = 0; k < 2 * D; ++k)
            acc = fmaf(feat[k], Wout[k * OUTD + t], acc);
        out[g * OUTD + t] = acc;
    }
}

// ---------------------------------------------------------------------------
extern "C" void kernel_launch(void* const* d_in, const int* in_sizes, int n_in,
                              void* d_out, int out_size, void* d_ws, size_t ws_size,
                              hipStream_t stream) {
    const int* nodes   = (const int*)d_in[0];
    const int* edges   = (const int*)d_in[1];
    const int* indices = (const int*)d_in[2];
    // d_in[3] = num_graphs (device scalar) — fixed at 512 for this problem
    const float* emb  = (const float*)d_in[4];
    const float* W0   = (const float*)d_in[5];
    const float* W1   = (const float*)d_in[6];
    const float* W2   = (const float*)d_in[7];
    const float* Wout = (const float*)d_in[8];
    const float* bout = (const float*)d_in[9];
    float* out = (float*)d_out;

    const int n = in_sizes[0];       // 50000
    const int E = in_sizes[1] / 2;   // 500000

    // -------- workspace layout (256B aligned) --------
    char* ws = (char*)d_ws;
    size_t off = 0;
    auto alloc = [&](size_t bytes) -> char* {
        char* p = ws + off;
        off = (off + bytes + 255) & ~(size_t)255;
        return p;
    };
    // zero-init region first (single memset): just the 3 allocation cursors
    int* totals = (int*)alloc(3 * sizeof(int));
    size_t zbytes = off;
    // non-zeroed (counts are fully overwritten by prep's scan blocks)
    int* cnt_in  = (int*)alloc(n * sizeof(int));
    int* cnt_out = (int*)alloc(n * sizeof(int));
    int* gcnt    = (int*)alloc(GRAPHS * sizeof(int));
    int* off_in  = (int*)alloc(n * sizeof(int));
    int* off_out = (int*)alloc(n * sizeof(int));
    int* goff    = (int*)alloc(GRAPHS * sizeof(int));
    u16* glist   = (u16*)alloc(n * sizeof(u16));
    u16* csr_in  = (u16*)alloc(E * sizeof(u16));
    u16* csr_out = (u16*)alloc(E * sizeof(u16));
    _Float16* Wpk = (_Float16*)alloc(3 * 3 * 4 * 8 * 64 * 8 * sizeof(_Float16));  // 288KB
    _Float16* B0 = (_Float16*)alloc((size_t)n * D * sizeof(_Float16));  // h
    _Float16* B1 = (_Float16*)alloc((size_t)n * D * sizeof(_Float16));  // agg1
    _Float16* B2 = (_Float16*)alloc((size_t)n * D * sizeof(_Float16));  // agg2
    (void)ws_size;

    hipMemsetAsync(d_ws, 0, zbytes, stream);

    // 1) prep: LDS key-range histograms (no global atomics) + gather + W pack
    int pblocks = NS + (n * 16 + 255) / 256;
    prep_kernel<<<pblocks, 256, 0, stream>>>(edges, indices, cnt_in, cnt_out, gcnt,
                                             nodes, emb, B0, W0, W1, W2, Wpk, E, n);
    // 2) offsets: wave-scan + atomic region allocation
    int oblocks = (n + 255) / 256;
    offsets_kernel<<<oblocks, 256, 0, stream>>>(cnt_in, off_in, cnt_out, off_out,
                                                gcnt, goff, totals, n);
    // 3) fill: key-range blocks, LDS cursors, clustered region writes
    fill_kernel<<<NS, 256, 0, stream>>>(edges, indices, off_in, off_out, goff,
                                        csr_in, csr_out, glist, E, n);

    // 3 GNN layers
    int ablocks = (n + 15) / 16;
    int tblocks = (n + 63) / 64;
    for (int l = 0; l < 3; ++l) {
        aggregate_kernel<<<ablocks, 256, 0, stream>>>(B0, csr_in, off_in, cnt_in,
                                                      csr_out, off_out, cnt_out, B1, B2, n);
        transform_mfma<<<tblocks, 128, 0, stream>>>(B0, B1, B2,
                                                    Wpk + (size_t)l * 3 * 4 * 8 * 512,
                                                    B0, n);
    }

    // pooling + head (no atomics)
    pool_head_kernel<<<GRAPHS, 128, 0, stream>>>(B0, glist, goff, gcnt, Wout, bout, out);
}

// Round 11
// 314.207 us; speedup vs baseline: 3.7337x; 3.7337x over previous
//
#include <hip/hip_runtime.h>
#include <hip/hip_bf16.h>

// Problem constants (fixed by the reference problem)
#define D 128
#define GRAPHS 512
#define OUTD 64
#define NR 64          // key ranges (exclusive node range per range-index)
#define NSL 16         // edge-list slices
#define NSCAN (NR * NSL)   // 1024 scan/fill blocks
#define LRANGE 800     // LDS counters per block (>= ceil(50000/64) = 782)

typedef _Float16 half4v __attribute__((ext_vector_type(4)));
typedef _Float16 half8v __attribute__((ext_vector_type(8)));
typedef float float4v __attribute__((ext_vector_type(4)));
typedef float float8v __attribute__((ext_vector_type(8)));
typedef unsigned short u16;

// ---------------------------------------------------------------------------
// Prep (fused): blocks 0..NSCAN-1 = (range r, slice s) histogram blocks — each
// streams ONLY slice s of the edge list (int4), counts keys in range r in LDS
// (no global atomics), writes per-slice partial counts pc[s][v] coalesced.
// 1024 blocks -> real occupancy (round-10 lesson: 64 blocks = 2.9% occ, 672us).
// Remaining blocks stream h0 = fp16(emb[nodes]) + W fragment pack in parallel.
// W pack layout (per layer): [src(3)][ks(4)][nf(8)][lane(64)][j(8)].
// ---------------------------------------------------------------------------
__global__ __launch_bounds__(256) void prep_kernel(
    const int* __restrict__ edges, const int* __restrict__ indices,
    int* __restrict__ pc_in, int* __restrict__ pc_out, int* __restrict__ pc_g,
    const int* __restrict__ nodes, const float* __restrict__ emb,
    _Float16* __restrict__ h,
    const float* __restrict__ W0, const float* __restrict__ W1,
    const float* __restrict__ W2, _Float16* __restrict__ Wpk,
    int E, int n) {
    int tid = threadIdx.x;
    if (blockIdx.x < NSCAN) {
        __shared__ int lin[LRANGE];
        __shared__ int lout[LRANGE];
        int s = blockIdx.x >> 6;          // slice (NR = 64)
        int r = blockIdx.x & (NR - 1);    // range
        int range = (n + NR - 1) / NR;
        int lo = r * range, hi = min(lo + range, n), len = hi - lo;
        for (int j = tid; j < len; j += 256) { lin[j] = 0; lout[j] = 0; }
        __syncthreads();
        int echunk = (((E + NSL - 1) / NSL) + 3) & ~3;
        int elo = s * echunk, ehi = min(elo + echunk, E);
#define HI(arr, k) { unsigned r_ = (unsigned)((k) - lo); if (r_ < (unsigned)len) atomicAdd(&arr[r_], 1); }
        {
            const int4* s4 = (const int4*)(edges + elo);
            const int4* d4 = (const int4*)(edges + E + elo);
            int m4 = (ehi - elo) >> 2;
            for (int it = tid; it < m4; it += 256) {
                int4 sv = s4[it], dv = d4[it];
                HI(lin, dv.x) HI(lin, dv.y) HI(lin, dv.z) HI(lin, dv.w)
                HI(lout, sv.x) HI(lout, sv.y) HI(lout, sv.z) HI(lout, sv.w)
            }
            for (int e = elo + m4 * 4 + tid; e < ehi; e += 256) {
                HI(lin, edges[E + e])
                HI(lout, edges[e])
            }
        }
#undef HI
        __syncthreads();
        for (int j = tid; j < len; j += 256) {
            pc_in[s * n + lo + j] = lin[j];
            pc_out[s * n + lo + j] = lout[j];
        }
        // graph counts: range r owns graphs [r*8, r*8+8)
        int grange = (GRAPHS + NR - 1) / NR;
        int glo = r * grange, ghi = min(glo + grange, GRAPHS), glen = ghi - glo;
        __syncthreads();
        for (int j = tid; j < glen; j += 256) lin[j] = 0;
        __syncthreads();
        int ichunk = (((n + NSL - 1) / NSL) + 3) & ~3;
        int ilo = s * ichunk, ihi = min(ilo + ichunk, n);
#define GH(k) { unsigned r_ = (unsigned)((k) - glo); if (r_ < (unsigned)glen) atomicAdd(&lin[r_], 1); }
        {
            const int4* i4 = (const int4*)(indices + ilo);
            int g4 = (ihi - ilo) >> 2;
            for (int it = tid; it < g4; it += 256) {
                int4 v = i4[it];
                GH(v.x) GH(v.y) GH(v.z) GH(v.w)
            }
            for (int e = ilo + g4 * 4 + tid; e < ihi; e += 256) GH(indices[e])
        }
#undef GH
        __syncthreads();
        for (int j = tid; j < glen; j += 256) pc_g[s * GRAPHS + glo + j] = lin[j];
        return;
    }
    // ---- stream role: gather + W pack ----
    int i = (blockIdx.x - NSCAN) * 256 + tid;
    if (i < n * 16) {   // gather: n*16 half8 chunks (16B/lane)
        int v = i >> 4, q = i & 15;
        const float4* e4 = (const float4*)emb + (size_t)nodes[v] * 32 + q * 2;
        float4 f0 = e4[0];
        float4 f1 = e4[1];
        half8v o = {(_Float16)f0.x, (_Float16)f0.y, (_Float16)f0.z, (_Float16)f0.w,
                    (_Float16)f1.x, (_Float16)f1.y, (_Float16)f1.z, (_Float16)f1.w};
        ((half8v*)h)[i] = o;
    }
    if (i < 36864) {    // 3 layers * 3 srcs * 4 ks * 8 nf * 64 lanes * 2 (j4) quads
        int j4 = (i & 1) * 4;
        int t = i >> 1;
        int lane = t & 63; t >>= 6;
        int nf = t & 7;   t >>= 3;
        int ks = t & 3;   t >>= 2;
        int src = t % 3;
        int l = t / 3;
        const float* W = (src == 0 ? W0 : (src == 1 ? W1 : W2)) + l * D * D;
        int col = nf * 16 + (lane & 15);
        int k = ks * 32 + (lane >> 4) * 8 + j4;
        float4 f = *(const float4*)&W[col * D + k];
        half4v o = {(_Float16)f.x, (_Float16)f.y, (_Float16)f.z, (_Float16)f.w};
        _Float16* dst = Wpk + ((size_t)(((l * 3 + src) * 4 + ks) * 8 + nf) * 64 + lane) * 8 + j4;
        *(half4v*)dst = o;
    }
}

// ---------------------------------------------------------------------------
// Offsets: per key, sum the NSL partial counts -> total; wave-scan + atomic
// region allocation for a contiguous per-key region; emit per-slice bases
// o16[s][v] so the atomic-free fill blocks can seed their LDS cursors.
// ---------------------------------------------------------------------------
__global__ __launch_bounds__(256) void offsets_kernel(
    const int* __restrict__ pc_in, int* __restrict__ o16_in,
    int* __restrict__ off_in, int* __restrict__ tot_in,
    const int* __restrict__ pc_out, int* __restrict__ o16_out,
    int* __restrict__ off_out, int* __restrict__ tot_out,
    const int* __restrict__ pc_g, int* __restrict__ o16_g,
    int* __restrict__ goff, int* __restrict__ gtot,
    int* totals, int n) {
    __shared__ int ws[8];
    int tid = threadIdx.x;
    int lane = tid & 63, wid = tid >> 6;
    int i = blockIdx.x * 256 + tid;

#define SCAN16(pc, o16, off, tot_arr, total, len)                          \
    do {                                                                   \
        int part_[NSL]; int tot_ = 0;                                      \
        if (i < (len)) {                                                   \
            _Pragma("unroll") for (int k_ = 0; k_ < NSL; ++k_) {           \
                part_[k_] = (pc)[k_ * (len) + i]; tot_ += part_[k_];       \
            }                                                              \
        }                                                                  \
        int v_ = tot_;                                                     \
        _Pragma("unroll") for (int d_ = 1; d_ < 64; d_ <<= 1) {            \
            int t_ = __shfl_up(v_, d_, 64);                                \
            if (lane >= d_) v_ += t_;                                      \
        }                                                                  \
        if (lane == 63) ws[wid] = v_;                                      \
        __syncthreads();                                                   \
        if (tid == 0) {                                                    \
            int s_ = 0;                                                    \
            for (int k_ = 0; k_ < 4; ++k_) { int t_ = ws[k_]; ws[k_] = s_; s_ += t_; } \
            ws[4] = atomicAdd((total), s_);                                \
        }                                                                  \
        __syncthreads();                                                   \
        if (i < (len)) {                                                   \
            int run_ = ws[4] + ws[wid] + v_ - tot_;                        \
            (off)[i] = run_; (tot_arr)[i] = tot_;                          \
            _Pragma("unroll") for (int k_ = 0; k_ < NSL; ++k_) {           \
                (o16)[k_ * (len) + i] = run_; run_ += part_[k_];           \
            }                                                              \
        }                                                                  \
        __syncthreads();                                                   \
    } while (0)

    SCAN16(pc_in, o16_in, off_in, tot_in, &totals[0], n);
    SCAN16(pc_out, o16_out, off_out, tot_out, &totals[1], n);
    if (blockIdx.x < (GRAPHS + 255) / 256)
        SCAN16(pc_g, o16_g, goff, gtot, &totals[2], GRAPHS);
#undef SCAN16
}

// ---------------------------------------------------------------------------
// Fill: 1024 (range, slice) blocks. LDS cursors seeded from the per-slice
// bases -> slot uniqueness via LDS atomics only; every block's writes land in
// its own contiguous sub-regions. Single fused edge scan (both directions,
// payload from the paired int4 — no scalar loads). Third pass fills glist.
// ---------------------------------------------------------------------------
__global__ __launch_bounds__(256) void fill_kernel(
    const int* __restrict__ edges, const int* __restrict__ indices,
    const int* __restrict__ o16_in, const int* __restrict__ o16_out,
    const int* __restrict__ o16_g,
    u16* __restrict__ csr_in, u16* __restrict__ csr_out, u16* __restrict__ glist,
    int E, int n) {
    __shared__ int cin[LRANGE];
    __shared__ int cout[LRANGE];
    __shared__ int cg[8];
    int tid = threadIdx.x;
    int s = blockIdx.x >> 6;
    int r = blockIdx.x & (NR - 1);
    int range = (n + NR - 1) / NR;
    int lo = r * range, hi = min(lo + range, n), len = hi - lo;
    int grange = (GRAPHS + NR - 1) / NR;
    int glo = r * grange, ghi = min(glo + grange, GRAPHS), glen = ghi - glo;
    for (int j = tid; j < len; j += 256) {
        cin[j] = o16_in[s * n + lo + j];
        cout[j] = o16_out[s * n + lo + j];
    }
    for (int j = tid; j < glen; j += 256) cg[j] = o16_g[s * GRAPHS + glo + j];
    __syncthreads();

    int echunk = (((E + NSL - 1) / NSL) + 3) & ~3;
    int elo = s * echunk, ehi = min(elo + echunk, E);
#define FIN(k, pay) { unsigned r_ = (unsigned)((k) - lo); if (r_ < (unsigned)len) { \
        int p_ = atomicAdd(&cin[r_], 1); csr_in[p_] = (u16)(pay); } }
#define FOUT(k, pay) { unsigned r_ = (unsigned)((k) - lo); if (r_ < (unsigned)len) { \
        int p_ = atomicAdd(&cout[r_], 1); csr_out[p_] = (u16)(pay); } }
    {
        const int4* s4 = (const int4*)(edges + elo);
        const int4* d4 = (const int4*)(edges + E + elo);
        int m4 = (ehi - elo) >> 2;
        for (int it = tid; it < m4; it += 256) {
            int4 sv = s4[it], dv = d4[it];
            FIN(dv.x, sv.x) FIN(dv.y, sv.y) FIN(dv.z, sv.z) FIN(dv.w, sv.w)
            FOUT(sv.x, dv.x) FOUT(sv.y, dv.y) FOUT(sv.z, dv.z) FOUT(sv.w, dv.w)
        }
        for (int e = elo + m4 * 4 + tid; e < ehi; e += 256) {
            int se = edges[e], de = edges[E + e];
            FIN(de, se)
            FOUT(se, de)
        }
    }
#undef FIN
#undef FOUT
    // glist (key = graph, payload = node id)
#define FG(g, vv) { unsigned r_ = (unsigned)((g) - glo); if (r_ < (unsigned)glen) { \
        int p_ = atomicAdd(&cg[r_], 1); glist[p_] = (u16)(vv); } }
    {
        int ichunk = (((n + NSL - 1) / NSL) + 3) & ~3;
        int ilo = s * ichunk, ihi = min(ilo + ichunk, n);
        const int4* i4 = (const int4*)(indices + ilo);
        int g4 = (ihi - ilo) >> 2;
        for (int it = tid; it < g4; it += 256) {
            int4 v = i4[it];
            int e = ilo + it * 4;
            FG(v.x, e) FG(v.y, e + 1) FG(v.z, e + 2) FG(v.w, e + 3)
        }
        for (int e = ilo + g4 * 4 + tid; e < ihi; e += 256) FG(indices[e], e)
    }
#undef FG
}

// ---------------------------------------------------------------------------
// Aggregation (fp16 h): 16-lane group per node, lane holds 8 fp16 (16B).
// x4 unroll -> 4 independent 16B loads in flight per group. fp32 accumulate.
// ---------------------------------------------------------------------------
__global__ __launch_bounds__(256) void aggregate_kernel(
    const _Float16* __restrict__ h,
    const u16* __restrict__ csr_in, const int* __restrict__ off_in, const int* __restrict__ cnt_in,
    const u16* __restrict__ csr_out, const int* __restrict__ off_out, const int* __restrict__ cnt_out,
    _Float16* __restrict__ agg1, _Float16* __restrict__ agg2, int n) {
    int grp = threadIdx.x >> 4;   // 16 nodes / block
    int lane = threadIdx.x & 15;
    int v = blockIdx.x * 16 + grp;
    if (v >= n) return;
    int s1 = off_in[v], c1 = cnt_in[v];
    int s2 = off_out[v], c2 = cnt_out[v];
    float invd = 1.0f / fmaxf((float)(c1 + c2), 1.0f);
    const half8v* h8 = (const half8v*)h;

    float8v a1 = {0.f, 0.f, 0.f, 0.f, 0.f, 0.f, 0.f, 0.f};
    int i = 0;
    for (; i + 4 <= c1; i += 4) {
        int u0 = csr_in[s1 + i], u1 = csr_in[s1 + i + 1];
        int u2 = csr_in[s1 + i + 2], u3 = csr_in[s1 + i + 3];
        half8v p0 = h8[u0 * 16 + lane];
        half8v p1 = h8[u1 * 16 + lane];
        half8v p2 = h8[u2 * 16 + lane];
        half8v p3 = h8[u3 * 16 + lane];
        a1 += (__builtin_convertvector(p0, float8v) + __builtin_convertvector(p1, float8v)) +
              (__builtin_convertvector(p2, float8v) + __builtin_convertvector(p3, float8v));
    }
    for (; i < c1; ++i)
        a1 += __builtin_convertvector(h8[csr_in[s1 + i] * 16 + lane], float8v);

    float8v a2 = {0.f, 0.f, 0.f, 0.f, 0.f, 0.f, 0.f, 0.f};
    i = 0;
    for (; i + 4 <= c2; i += 4) {
        int u0 = csr_out[s2 + i], u1 = csr_out[s2 + i + 1];
        int u2 = csr_out[s2 + i + 2], u3 = csr_out[s2 + i + 3];
        half8v p0 = h8[u0 * 16 + lane];
        half8v p1 = h8[u1 * 16 + lane];
        half8v p2 = h8[u2 * 16 + lane];
        half8v p3 = h8[u3 * 16 + lane];
        a2 += (__builtin_convertvector(p0, float8v) + __builtin_convertvector(p1, float8v)) +
              (__builtin_convertvector(p2, float8v) + __builtin_convertvector(p3, float8v));
    }
    for (; i < c2; ++i)
        a2 += __builtin_convertvector(h8[csr_out[s2 + i] * 16 + lane], float8v);

    a1 *= invd;
    a2 *= invd;
    ((half8v*)agg1)[v * 16 + lane] = __builtin_convertvector(a1, half8v);
    ((half8v*)agg2)[v * 16 + lane] = __builtin_convertvector(a2, half8v);
}

// ---------------------------------------------------------------------------
// MFMA transform: Hout = relu(H@W0^T + A1@W1^T + A2@W2^T), all fp16 in/out,
// fp32 accumulate. BM=64 rows/block, 2 waves; wave w owns rows w*32..+31
// (2 m-frags x 8 n-frags of 16x16x32_f16). A-frags read straight from global
// (own rows only -> self-aliasing with Hout is safe); B-frags read from the
// pre-packed, L2-resident Wpk (lane*16B contiguous). No LDS in the K-loop.
// Fragment maps: A/B k = 8*(lane>>4)+j (m92-verified contiguous-k);
// C/D n = lane&15, m = 4*(lane>>4)+reg (m89/m91-verified).
// ---------------------------------------------------------------------------
__global__ __launch_bounds__(128) void transform_mfma(
    const _Float16* __restrict__ Xh, const _Float16* __restrict__ A1,
    const _Float16* __restrict__ A2, const _Float16* __restrict__ Wl,
    _Float16* __restrict__ Hout, int n) {
    __shared__ _Float16 Hs[64][136];   // epilogue transpose tile (stride 272B)
    int tid = threadIdx.x;
    int w = tid >> 6, lane = tid & 63;
    int rbase = blockIdx.x * 64 + w * 32;
    int m0 = lane & 15;
    int kg = lane >> 4;                 // 0..3
    int r0 = min(rbase + m0, n - 1);        // clamp keeps tail loads in-bounds
    int r1 = min(rbase + 16 + m0, n - 1);

    const _Float16* srcs[3] = {Xh, A1, A2};

    float4v acc[2][8];
#pragma unroll
    for (int mf = 0; mf < 2; ++mf)
#pragma unroll
        for (int nf = 0; nf < 8; ++nf) acc[mf][nf] = (float4v){0.f, 0.f, 0.f, 0.f};

#define LOAD_STEP(stp, A0v, A1v, Bv)                                              \
    do {                                                                          \
        const int src_ = (stp) >> 2, ks_ = (stp) & 3;                             \
        const _Float16* X_ = srcs[src_];                                          \
        A0v = *(const half8v*)(X_ + (size_t)r0 * D + ks_ * 32 + kg * 8);          \
        A1v = *(const half8v*)(X_ + (size_t)r1 * D + ks_ * 32 + kg * 8);          \
        const _Float16* wp_ = Wl + (size_t)((src_ * 4 + ks_) * 8) * 512 + lane * 8; \
        _Pragma("unroll") for (int nf_ = 0; nf_ < 8; ++nf_)                       \
            Bv[nf_] = *(const half8v*)(wp_ + nf_ * 512);                          \
    } while (0)

    half8v a0c, a1c, bc[8], a0n, a1n, bn[8];
    LOAD_STEP(0, a0c, a1c, bc);
#pragma unroll
    for (int step = 0; step < 12; ++step) {
        if (step < 11) LOAD_STEP(step + 1, a0n, a1n, bn);
#pragma unroll
        for (int nf = 0; nf < 8; ++nf) {
            acc[0][nf] = __builtin_amdgcn_mfma_f32_16x16x32_f16(a0c, bc[nf], acc[0][nf], 0, 0, 0);
            acc[1][nf] = __builtin_amdgcn_mfma_f32_16x16x32_f16(a1c, bc[nf], acc[1][nf], 0, 0, 0);
        }
        a0c = a0n; a1c = a1n;
#pragma unroll
        for (int nf = 0; nf < 8; ++nf) bc[nf] = bn[nf];
    }
#undef LOAD_STEP

    // epilogue: relu -> LDS transpose -> coalesced fp16 row stores
#pragma unroll
    for (int mf = 0; mf < 2; ++mf)
#pragma unroll
        for (int nf = 0; nf < 8; ++nf)
#pragma unroll
            for (int r = 0; r < 4; ++r) {
                int row = w * 32 + mf * 16 + kg * 4 + r;
                int col = nf * 16 + m0;
                Hs[row][col] = (_Float16)fmaxf(acc[mf][nf][r], 0.0f);
            }
    __syncthreads();
#pragma unroll
    for (int it = 0; it < 8; ++it) {
        int id = tid + it * 128;        // 0..1023 = 64 rows x 16 chunks of 8 fp16
        int row = id >> 4, c8 = id & 15;
        int grow = blockIdx.x * 64 + row;
        if (grow < n)
            *(half8v*)(Hout + (size_t)grow * D + c8 * 8) = *(const half8v*)&Hs[row][c8 * 8];
    }
}

// ---------------------------------------------------------------------------
// Graph pooling + output head, fused. One block (128 threads) per graph.
// mean + max over the graph's node list (h >= 0 post-ReLU so max-init 0
// matches torch_scatter's empty->0 default), then out = [mean|max]@Wout+bout.
// ---------------------------------------------------------------------------
__global__ __launch_bounds__(128) void pool_head_kernel(
    const _Float16* __restrict__ h, const u16* __restrict__ glist,
    const int* __restrict__ goff, const int* __restrict__ gcnt,
    const float* __restrict__ Wout, const float* __restrict__ bout,
    float* __restrict__ out) {
    __shared__ float feat[2 * D];
    int g = blockIdx.x;
    int t = threadIdx.x;
    int s = goff[g], c = gcnt[g];
    float sum = 0.0f, mx = 0.0f;
    int i = 0;
    for (; i + 4 <= c; i += 4) {
        int v0 = glist[s + i], v1 = glist[s + i + 1];
        int v2 = glist[s + i + 2], v3 = glist[s + i + 3];
        float a = (float)h[(size_t)v0 * D + t];
        float b = (float)h[(size_t)v1 * D + t];
        float cc = (float)h[(size_t)v2 * D + t];
        float d = (float)h[(size_t)v3 * D + t];
        sum += (a + b) + (cc + d);
        mx = fmaxf(mx, fmaxf(fmaxf(a, b), fmaxf(cc, d)));
    }
    for (; i < c; ++i) {
        float a = (float)h[(size_t)glist[s + i] * D + t];
        sum += a;
        mx = fmaxf(mx, a);
    }
    feat[t] = sum / fmaxf((float)c, 1.0f);
    feat[D + t] = mx;
    __syncthreads();
    if (t < OUTD) {
        float acc = bout[t];
#pragma unroll 8
        for (int k = 0; k < 2 * D; ++k)
            acc = fmaf(feat[k], Wout[k * OUTD + t], acc);
        out[g * OUTD + t] = acc;
    }
}

// ---------------------------------------------------------------------------
extern "C" void kernel_launch(void* const* d_in, const int* in_sizes, int n_in,
                              void* d_out, int out_size, void* d_ws, size_t ws_size,
                              hipStream_t stream) {
    const int* nodes   = (const int*)d_in[0];
    const int* edges   = (const int*)d_in[1];
    const int* indices = (const int*)d_in[2];
    // d_in[3] = num_graphs (device scalar) — fixed at 512 for this problem
    const float* emb  = (const float*)d_in[4];
    const float* W0   = (const float*)d_in[5];
    const float* W1   = (const float*)d_in[6];
    const float* W2   = (const float*)d_in[7];
    const float* Wout = (const float*)d_in[8];
    const float* bout = (const float*)d_in[9];
    float* out = (float*)d_out;

    const int n = in_sizes[0];       // 50000
    const int E = in_sizes[1] / 2;   // 500000

    // -------- workspace layout (256B aligned) --------
    char* ws = (char*)d_ws;
    size_t off = 0;
    auto alloc = [&](size_t bytes) -> char* {
        char* p = ws + off;
        off = (off + bytes + 255) & ~(size_t)255;
        return p;
    };
    // zero-init region first (single memset): just the 3 allocation cursors
    int* totals = (int*)alloc(3 * sizeof(int));
    size_t zbytes = off;
    // non-zeroed (partial counts fully overwritten by prep's scan blocks)
    int* pc_in   = (int*)alloc((size_t)NSL * n * sizeof(int));
    int* pc_out  = (int*)alloc((size_t)NSL * n * sizeof(int));
    int* pc_g    = (int*)alloc(NSL * GRAPHS * sizeof(int));
    int* o16_in  = (int*)alloc((size_t)NSL * n * sizeof(int));
    int* o16_out = (int*)alloc((size_t)NSL * n * sizeof(int));
    int* o16_g   = (int*)alloc(NSL * GRAPHS * sizeof(int));
    int* off_in  = (int*)alloc(n * sizeof(int));
    int* off_out = (int*)alloc(n * sizeof(int));
    int* tot_in  = (int*)alloc(n * sizeof(int));
    int* tot_out = (int*)alloc(n * sizeof(int));
    int* goff    = (int*)alloc(GRAPHS * sizeof(int));
    int* gtot    = (int*)alloc(GRAPHS * sizeof(int));
    u16* glist   = (u16*)alloc(n * sizeof(u16));
    u16* csr_in  = (u16*)alloc(E * sizeof(u16));
    u16* csr_out = (u16*)alloc(E * sizeof(u16));
    _Float16* Wpk = (_Float16*)alloc(3 * 3 * 4 * 8 * 64 * 8 * sizeof(_Float16));  // 288KB
    _Float16* B0 = (_Float16*)alloc((size_t)n * D * sizeof(_Float16));  // h
    _Float16* B1 = (_Float16*)alloc((size_t)n * D * sizeof(_Float16));  // agg1
    _Float16* B2 = (_Float16*)alloc((size_t)n * D * sizeof(_Float16));  // agg2
    (void)ws_size;

    hipMemsetAsync(d_ws, 0, zbytes, stream);

    // 1) prep: (range x slice) LDS histograms (no global atomics) + gather + W pack
    int pblocks = NSCAN + (n * 16 + 255) / 256;
    prep_kernel<<<pblocks, 256, 0, stream>>>(edges, indices, pc_in, pc_out, pc_g,
                                             nodes, emb, B0, W0, W1, W2, Wpk, E, n);
    // 2) offsets: sum NSL partials -> region alloc -> per-slice bases
    int oblocks = (n + 255) / 256;
    offsets_kernel<<<oblocks, 256, 0, stream>>>(pc_in, o16_in, off_in, tot_in,
                                                pc_out, o16_out, off_out, tot_out,
                                                pc_g, o16_g, goff, gtot, totals, n);
    // 3) fill: 1024 (range x slice) blocks, LDS cursors, atomic-free slots
    fill_kernel<<<NSCAN, 256, 0, stream>>>(edges, indices, o16_in, o16_out, o16_g,
                                           csr_in, csr_out, glist, E, n);

    // 3 GNN layers
    int ablocks = (n + 15) / 16;
    int tblocks = (n + 63) / 64;
    for (int l = 0; l < 3; ++l) {
        aggregate_kernel<<<ablocks, 256, 0, stream>>>(B0, csr_in, off_in, tot_in,
                                                      csr_out, off_out, tot_out, B1, B2, n);
        transform_mfma<<<tblocks, 128, 0, stream>>>(B0, B1, B2,
                                                    Wpk + (size_t)l * 3 * 4 * 8 * 512,
                                                    B0, n);
    }

    // pooling + head (no atomics)
    pool_head_kernel<<<GRAPHS, 128, 0, stream>>>(B0, glist, goff, gtot, Wout, bout, out);
}